// Round 5
// baseline (863.345 us; speedup 1.0000x reference)
//
#include <hip/hip_runtime.h>
#include <hip/hip_bf16.h>
#include <stdint.h>

// Problem constants
#define NQ    2304          // H*W = 48*48 tokens
#define MROWS 4608          // B*NQ
#define DIMC  768
#define NHEAD 12
#define HEADS 24            // B*NH
#define HD    64

typedef unsigned int uint;
typedef unsigned short u16;
typedef __attribute__((ext_vector_type(8))) short s16x8;   // 8 bf16 = 4 VGPR
typedef __attribute__((ext_vector_type(4))) float f32x4;   // mfma acc

#define MFMA16(a, b, c) __builtin_amdgcn_mfma_f32_16x16x32_bf16((a), (b), (c), 0, 0, 0)

static __device__ __forceinline__ float bfbits2f(uint u) {
  union { uint i; float f; } c; c.i = u << 16; return c.f;
}
static __device__ __forceinline__ u16 f2bf(float f) {
  __hip_bfloat16 h = __float2bfloat16(f);
  union { __hip_bfloat16 h; u16 u; } c; c.h = h; return c.u;
}
static __device__ __forceinline__ void dec8(uint4 p, float* f) {
  f[0] = bfbits2f(p.x & 0xFFFFu); f[1] = bfbits2f(p.x >> 16);
  f[2] = bfbits2f(p.y & 0xFFFFu); f[3] = bfbits2f(p.y >> 16);
  f[4] = bfbits2f(p.z & 0xFFFFu); f[5] = bfbits2f(p.z >> 16);
  f[6] = bfbits2f(p.w & 0xFFFFu); f[7] = bfbits2f(p.w >> 16);
}
// dual-dtype 8-element load -> fp32 (bf=1: bf16, bf=0: fp32)
static __device__ __forceinline__ void ld8(const void* p, size_t idx, int bf, float* f) {
  if (bf) { dec8(*(const uint4*)((const u16*)p + idx), f); }
  else {
    const float4* q = (const float4*)((const float*)p + idx);
    float4 a = q[0], b = q[1];
    f[0] = a.x; f[1] = a.y; f[2] = a.z; f[3] = a.w;
    f[4] = b.x; f[5] = b.y; f[6] = b.z; f[7] = b.w;
  }
}
static __device__ __forceinline__ float ld1(const void* p, size_t idx, int bf) {
  return bf ? bfbits2f(((const u16*)p)[idx]) : ((const float*)p)[idx];
}
// dual-dtype 8-element load -> packed bf16 (uint4)
static __device__ __forceinline__ uint4 ld8_to_bf(const void* p, size_t idx, int bf) {
  if (bf) return *(const uint4*)((const u16*)p + idx);
  float f[8]; ld8(p, idx, 0, f);
  uint4 u;
  u.x = (uint)f2bf(f[0]) | ((uint)f2bf(f[1]) << 16);
  u.y = (uint)f2bf(f[2]) | ((uint)f2bf(f[3]) << 16);
  u.z = (uint)f2bf(f[4]) | ((uint)f2bf(f[5]) << 16);
  u.w = (uint)f2bf(f[6]) | ((uint)f2bf(f[7]) << 16);
  return u;
}

// ---------------------------------------------------------------------------
// K0: dtype detector (unchanged — PASSED; do not touch).
// ---------------------------------------------------------------------------
__global__ __launch_bounds__(64) void detect_k(const u16* __restrict__ x,
                                               int* __restrict__ mode) {
  int t = threadIdx.x;
  int cnt = 0;
  for (int i = 0; i < 32; ++i) {
    uint u = x[(size_t)(t * 32 + i) * 2];
    uint e = (u >> 7) & 0xFFu;
    uint mag = u & 0x7FFFu;
    if (mag == 0 || (e >= 113 && e <= 133)) cnt++;
  }
#pragma unroll
  for (int d = 1; d < 64; d <<= 1) cnt += __shfl_xor(cnt, d);
  if (t == 0) mode[0] = (cnt > 1024) ? 1 : 0;
}

// ---------------------------------------------------------------------------
// K1: QKV projection, MFMA.  V stored TRANSPOSED: Vt[(bh*HD + d)*NQ + n]
// so attn loads V^T B-frags directly from global. Q/K row-major. (unchanged)
// ---------------------------------------------------------------------------
__global__ __launch_bounds__(256) void qkv_gemm_k(
    const void* __restrict__ Xp, const void* __restrict__ Wp,
    const void* __restrict__ Bq, const int* __restrict__ mode,
    u16* __restrict__ Q, u16* __restrict__ K, u16* __restrict__ Vt)
{
  __shared__ __align__(16) u16 As[128][40];
  __shared__ __align__(16) u16 Bs[128][40];
  const int bf = mode[0];
  const int t = threadIdx.x;
  const int w = t >> 6, l15 = t & 15, quad = (t >> 4) & 3;
  const int wr = w >> 1, wc = w & 1;
  const int row0 = blockIdx.y << 7, col0 = blockIdx.x << 7;
  const int lr = t >> 1, lk = (t & 1) << 4;

  f32x4 zero4 = {0.f, 0.f, 0.f, 0.f};
  f32x4 acc[4][4];
#pragma unroll
  for (int i = 0; i < 4; ++i)
#pragma unroll
    for (int j = 0; j < 4; ++j) acc[i][j] = zero4;

  for (int kt = 0; kt < DIMC; kt += 32) {
    __syncthreads();
    *(uint4*)&As[lr][lk]     = ld8_to_bf(Xp, (size_t)(row0 + lr) * DIMC + kt + lk, bf);
    *(uint4*)&As[lr][lk + 8] = ld8_to_bf(Xp, (size_t)(row0 + lr) * DIMC + kt + lk + 8, bf);
    *(uint4*)&Bs[lr][lk]     = ld8_to_bf(Wp, (size_t)(col0 + lr) * DIMC + kt + lk, bf);
    *(uint4*)&Bs[lr][lk + 8] = ld8_to_bf(Wp, (size_t)(col0 + lr) * DIMC + kt + lk + 8, bf);
    __syncthreads();
    s16x8 af[4], bfr[4];
#pragma unroll
    for (int i = 0; i < 4; ++i)
      af[i] = *(const s16x8*)&As[(wr << 6) + (i << 4) + l15][quad << 3];
#pragma unroll
    for (int j = 0; j < 4; ++j)
      bfr[j] = *(const s16x8*)&Bs[(wc << 6) + (j << 4) + l15][quad << 3];
#pragma unroll
    for (int i = 0; i < 4; ++i)
#pragma unroll
      for (int j = 0; j < 4; ++j)
        acc[i][j] = MFMA16(af[i], bfr[j], acc[i][j]);
  }

#pragma unroll
  for (int jt = 0; jt < 4; ++jt) {
    int col = col0 + (wc << 6) + (jt << 4) + l15;     // 0..2303
    int which = col / DIMC;
    int rem = col - which * DIMC;
    int head = rem >> 6, d = rem & 63;
    float bv = ld1(Bq, col, bf);
#pragma unroll
    for (int i = 0; i < 4; ++i)
#pragma unroll
      for (int r = 0; r < 4; ++r) {
        int mrow = row0 + (wr << 6) + (i << 4) + (quad << 2) + r;
        int b_ = (mrow >= NQ) ? 1 : 0;
        int n = mrow - b_ * NQ;
        u16 val = f2bf(acc[i][jt][r] + bv);
        size_t bh = (size_t)(b_ * NHEAD + head);
        if (which == 2)      Vt[(bh * HD + d) * NQ + n] = val;     // transposed
        else if (which == 1) K[(bh * NQ + n) * HD + d] = val;
        else                 Q[(bh * NQ + n) * HD + d] = val;
      }
  }
}

// ---------------------------------------------------------------------------
// K2: MFMA flash attention, round 5: SPLIT-K for wave-level parallelism.
//  Evidence r0-r4: latency-bound, ~1 resident block/CU (VGPR 144 > 128 cliff,
//  864-block grid = 3.4 blocks/CU backfill), time insensitive to traffic.
//  Fixes:
//   (a) split-K: block = (head, qtile, ksplit z of S). S picked by host from
//       ws_size (3/2/1). Partial O (f32) + l per split; combine_k merges.
//       No-max softmax is linear in partials -> math identical.
//   (b) VGPR < 128: bias loops reordered (outer v8, inner c, 24 accumulators)
//       -> no fq[64] array; main loop unchanged in content.
//   (c) bias tables f32; Bw transposed [qrow][48] -> per-tile reads are
//       4 x ds_read_b128 (4 consecutive kw, never wraps since kt0%48 in
//       {0,16,32}) + 2 scalar Bh reads. Was 16 scalar u16 reads + cvts.
//  Main loop: no barriers, no K/V LDS (direct global, L2-resident via
//  XCD head-grouping). LDS = f32 bias tables (28672 B).
// ---------------------------------------------------------------------------
__global__ __launch_bounds__(256) void attn_k(
    const u16* __restrict__ Qw, const u16* __restrict__ Kw,
    const u16* __restrict__ Vtg,
    const void* __restrict__ rph, const void* __restrict__ rpw,
    const int* __restrict__ mode,
    int S, float* __restrict__ Opart, float* __restrict__ Lpart,
    u16* __restrict__ Aout)
{
  __shared__ __align__(16) float BhS[4][48][20];   // [wave][kh][qrow]
  __shared__ __align__(16) float BwS[4][16][52];   // [wave][qrow][kw] (transposed!)

  const int bf = mode[0];
  // XCD swizzle: nwg = 864*S (div by 8). XCD x runs heads 3x..3x+2 only ->
  // per-XCD K/V working set 3 heads = 1.76 MB -> L2-resident.
  const int bid = blockIdx.x;
  const int xcd = bid & 7;
  const int local = bid >> 3;            // [0, 108*S)
  const int per_head = 36 * S;
  const int head_l = local / per_head;   // 0..2
  const int rem = local - head_l * per_head;
  const int qb = rem / S;
  const int z = rem - qb * S;
  const int bhd = xcd * 3 + head_l;
  const int q0 = qb << 6;
  const int span = NQ / S;               // 2304/1152/768; all multiples of 48&64
  const int kt_lo = z * span, kt_hi = kt_lo + span;

  const int t = threadIdx.x;
  const int w = t >> 6, l15 = t & 15, quad = (t >> 4) & 3;
  const float scale = 0.125f;   // 64^-0.5

  const u16* kbase  = Kw  + (size_t)bhd * NQ * HD;
  const u16* vtbase = Vtg + (size_t)bhd * HD * NQ;
  const int q0w = q0 + (w << 4);

  // ---- bias tables (per-wave slice). Loop order: outer v8, inner c ->
  // peak regs ~24 accumulators + 8 fq + 16 fh/fw (no fq[64]).
  {
    const int n = q0w + l15;
    const int qh = (n * 10923) >> 19;         // n/48
    const int qw_ = n - qh * 48;
    const u16* qr = Qw + ((size_t)bhd * NQ + n) * HD;
    float sh[12], sw2[12];
#pragma unroll
    for (int it = 0; it < 12; ++it) { sh[it] = 0.f; sw2[it] = 0.f; }
    for (int v8 = 0; v8 < 8; ++v8) {
      float fq8[8];
      dec8(*(const uint4*)(qr + (v8 << 3)), fq8);
#pragma unroll
      for (int it = 0; it < 12; ++it) {
        int c = (it << 2) + quad;             // 0..47
        float fh[8], fw[8];
        ld8(rph, (size_t)(qh - c + 47) * HD + (v8 << 3), bf, fh);
        ld8(rpw, (size_t)(qw_ - c + 47) * HD + (v8 << 3), bf, fw);
#pragma unroll
        for (int j = 0; j < 8; ++j) {
          sh[it] += fq8[j] * fh[j];
          sw2[it] += fq8[j] * fw[j];
        }
      }
    }
#pragma unroll
    for (int it = 0; it < 12; ++it) {
      int c = (it << 2) + quad;
      BhS[w][c][l15] = sh[it];
      BwS[w][l15][c] = sw2[it];
    }
  }
  __syncthreads();   // the only block barrier (bias tables visible)

  // Q B-frags (loop-invariant): B[n=qrow=l15][k=quad*8+j]
  const u16* qfrag = Qw + ((size_t)bhd * NQ + q0w + l15) * HD + (quad << 3);
  s16x8 qa0 = *(const s16x8*)(qfrag);
  s16x8 qa1 = *(const s16x8*)(qfrag + 32);

  f32x4 zero4 = {0.f, 0.f, 0.f, 0.f};
  f32x4 acc_o[4];
#pragma unroll
  for (int nc = 0; nc < 4; ++nc) acc_o[nc] = zero4;
  float l_st = 0.f;   // lane-local partial sum of exp(S); reduced in epilogue
  int km = 0;         // kt0 % 48; kt_lo % 48 == 0 for all splits

  for (int kt0 = kt_lo; kt0 < kt_hi; kt0 += 64) {
    // S^T = K Q^T : lane holds S[key = kt0+16*nc+4*quad+r][qrow = l15]
    f32x4 acc_s[4];
#pragma unroll
    for (int nc = 0; nc < 4; ++nc) {
      const u16* kp = kbase + (size_t)(kt0 + (nc << 4) + l15) * HD + (quad << 3);
      s16x8 kb0 = *(const s16x8*)(kp);
      s16x8 kb1 = *(const s16x8*)(kp + 32);
      f32x4 a = MFMA16(kb0, qa0, zero4);
      acc_s[nc] = MFMA16(kb1, qa1, a);
    }

    // V^T frag loads (half 0) issued now; latency flies under softmax VALU
    s16x8 vb0[4];
#pragma unroll
    for (int nc = 0; nc < 4; ++nc) {
      const u16* vp = vtbase + (size_t)((nc << 4) + l15) * NQ + kt0 + (quad << 3);
      vb0[nc] = *(const s16x8*)(vp);
    }

    // bias reads: Bh 2 scalars; Bw 4 x b128 (4 consecutive kw per nc-group)
    int kh0 = (kt0 * 10923) >> 19;
    float bh0v = BhS[w][kh0][l15];
    float bh1v = BhS[w][kh0 + 1][l15];       // kh0 <= 46 always
    int thr = (kh0 + 1) * 48 - kt0;          // local key >= thr -> kh0+1
    f32x4 bwv[4];
#pragma unroll
    for (int nc = 0; nc < 4; ++nc) {
      int bnc = km + (nc << 4);
      bnc = (bnc >= 48) ? bnc - 48 : bnc;    // in {0,16,32}; +4*quad+3 <= 47
      bwv[nc] = *(const f32x4*)&BwS[w][l15][bnc + (quad << 2)];
    }

    // scale + bias -> exp (no max subtraction: scores bounded)
    float sv[16];
    float sum = 0.f;
#pragma unroll
    for (int nc = 0; nc < 4; ++nc)
#pragma unroll
      for (int r = 0; r < 4; ++r) {
        int kl = (nc << 4) + (quad << 2) + r;
        float s = acc_s[nc][r] * scale + ((kl >= thr) ? bh1v : bh0v) + bwv[nc][r];
        s = __expf(s);
        sv[(nc << 2) + r] = s;
        sum += s;
      }
    l_st += sum;

    // P -> A-frags via cross-quad shfl exchange (two key-halves).
    // A[m=l15(qrow)][k=quad*8+j (key)].
    int srcA = ((quad & 1) << 5) + l15;   // source quad 2*(quad&1)
    int srcB = srcA + 16;                 // source quad 2*(quad&1)+1
    int hi = quad >> 1;
    // half 0: keys kt0+0..31
    {
      uint W0 = (uint)f2bf(sv[0]) | ((uint)f2bf(sv[1]) << 16);
      uint W1 = (uint)f2bf(sv[2]) | ((uint)f2bf(sv[3]) << 16);
      uint W2 = (uint)f2bf(sv[4]) | ((uint)f2bf(sv[5]) << 16);
      uint W3 = (uint)f2bf(sv[6]) | ((uint)f2bf(sv[7]) << 16);
      union { uint u[4]; s16x8 v; } pf;
      uint e0 = __shfl(W0, srcA), e1 = __shfl(W1, srcA), e2 = __shfl(W2, srcA), e3 = __shfl(W3, srcA);
      pf.u[0] = hi ? e2 : e0; pf.u[1] = hi ? e3 : e1;
      uint g0 = __shfl(W0, srcB), g1 = __shfl(W1, srcB), g2 = __shfl(W2, srcB), g3 = __shfl(W3, srcB);
      pf.u[2] = hi ? g2 : g0; pf.u[3] = hi ? g3 : g1;
#pragma unroll
      for (int nc = 0; nc < 4; ++nc)
        acc_o[nc] = MFMA16(pf.v, vb0[nc], acc_o[nc]);
    }
    // half 1: keys kt0+32..63 (V loads issued here, hidden by half-0 MFMAs)
    {
      s16x8 vb1[4];
#pragma unroll
      for (int nc = 0; nc < 4; ++nc) {
        const u16* vp = vtbase + (size_t)((nc << 4) + l15) * NQ + kt0 + 32 + (quad << 3);
        vb1[nc] = *(const s16x8*)(vp);
      }
      uint W4 = (uint)f2bf(sv[8])  | ((uint)f2bf(sv[9])  << 16);
      uint W5 = (uint)f2bf(sv[10]) | ((uint)f2bf(sv[11]) << 16);
      uint W6 = (uint)f2bf(sv[12]) | ((uint)f2bf(sv[13]) << 16);
      uint W7 = (uint)f2bf(sv[14]) | ((uint)f2bf(sv[15]) << 16);
      union { uint u[4]; s16x8 v; } pf;
      uint e0 = __shfl(W4, srcA), e1 = __shfl(W5, srcA), e2 = __shfl(W6, srcA), e3 = __shfl(W7, srcA);
      pf.u[0] = hi ? e2 : e0; pf.u[1] = hi ? e3 : e1;
      uint g0 = __shfl(W4, srcB), g1 = __shfl(W5, srcB), g2 = __shfl(W6, srcB), g3 = __shfl(W7, srcB);
      pf.u[2] = hi ? g2 : g0; pf.u[3] = hi ? g3 : g1;
#pragma unroll
      for (int nc = 0; nc < 4; ++nc)
        acc_o[nc] = MFMA16(pf.v, vb1[nc], acc_o[nc]);
    }
    km += 16;
    if (km >= 48) km -= 48;
  }

  // reduce l across quads (each lane then has full sum for qrow = q0w+l15)
  l_st += __shfl_xor(l_st, 16);
  l_st += __shfl_xor(l_st, 32);

  if (S > 1) {
    // partial path: unnormalized f32 O + l per split
    float* Op = Opart + ((size_t)(z * HEADS + bhd) * NQ + q0) * HD;
#pragma unroll
    for (int r = 0; r < 4; ++r) {
      int row = (w << 4) + (quad << 2) + r;
#pragma unroll
      for (int nc = 0; nc < 4; ++nc)
        Op[(size_t)row * HD + (nc << 4) + l15] = acc_o[nc][r];
    }
    if (quad == 0)
      Lpart[(size_t)(z * HEADS + bhd) * NQ + q0w + l15] = l_st;
  } else {
    // direct path: divide by l (broadcast from lane 20*quad+r), store bf16
    int b_ = bhd / NHEAD, head = bhd - b_ * NHEAD;
    float invl = 1.f / l_st;
    int bsrc = (quad << 4) + (quad << 2);
#pragma unroll
    for (int r = 0; r < 4; ++r) {
      float inv = __shfl(invl, bsrc + r);    // lane with l15 == 4*quad+r
      int token = q0 + (w << 4) + (quad << 2) + r;
      u16* dst = Aout + ((size_t)b_ * NQ + token) * DIMC + (head << 6);
#pragma unroll
      for (int nc = 0; nc < 4; ++nc)
        dst[(nc << 4) + l15] = f2bf(acc_o[nc][r] * inv);
    }
  }
}

// ---------------------------------------------------------------------------
// K2b: combine split-K partials: O = (sum_z O_z) / (sum_z l_z), store bf16
// into aout (b, token, head*64+d). Grid: 884736 threads, 4 f32 each.
// ---------------------------------------------------------------------------
__global__ __launch_bounds__(256) void combine_k(
    const float* __restrict__ Op, const float* __restrict__ Lp,
    int S, u16* __restrict__ Aout)
{
  int idx = blockIdx.x * 256 + threadIdx.x;   // 0 .. 884735
  int m = idx / 192;                          // row 0..4607 (DIMC/4 = 192)
  int cq = idx - m * 192;
  int ccol = cq << 2;                         // col of first of 4
  int head = ccol >> 6, d0 = ccol & 63;
  int b_ = (m >= NQ) ? 1 : 0;
  int n = m - b_ * NQ;
  int bh = b_ * NHEAD + head;
  float ox = 0.f, oy = 0.f, oz = 0.f, ow = 0.f, ls = 0.f;
  for (int zz = 0; zz < S; ++zz) {
    const float* ob = Op + ((size_t)(zz * HEADS + bh) * NQ + n) * HD + d0;
    float4 v = *(const float4*)ob;
    ox += v.x; oy += v.y; oz += v.z; ow += v.w;
    ls += Lp[(size_t)(zz * HEADS + bh) * NQ + n];
  }
  float inv = 1.f / ls;
  u16* dst = Aout + (size_t)m * DIMC + ccol;
  dst[0] = f2bf(ox * inv); dst[1] = f2bf(oy * inv);
  dst[2] = f2bf(oz * inv); dst[3] = f2bf(ow * inv);
}

// ---------------------------------------------------------------------------
// K3: output projection, MFMA (unchanged).
// ---------------------------------------------------------------------------
__global__ __launch_bounds__(256) void proj_gemm_k(
    const u16* __restrict__ A, const void* __restrict__ Wp,
    const void* __restrict__ Bp, const int* __restrict__ mode,
    void* __restrict__ Out)
{
  __shared__ __align__(16) u16 As[128][40];
  __shared__ __align__(16) u16 Bs[128][40];
  const int bf = mode[0];
  const int t = threadIdx.x;
  const int w = t >> 6, l15 = t & 15, quad = (t >> 4) & 3;
  const int wr = w >> 1, wc = w & 1;
  const int row0 = blockIdx.y << 7, col0 = blockIdx.x << 7;
  const int lr = t >> 1, lk = (t & 1) << 4;

  f32x4 zero4 = {0.f, 0.f, 0.f, 0.f};
  f32x4 acc[4][4];
#pragma unroll
  for (int i = 0; i < 4; ++i)
#pragma unroll
    for (int j = 0; j < 4; ++j) acc[i][j] = zero4;

  for (int kt = 0; kt < DIMC; kt += 32) {
    __syncthreads();
    *(uint4*)&As[lr][lk]     = *(const uint4*)(A + (size_t)(row0 + lr) * DIMC + kt + lk);
    *(uint4*)&As[lr][lk + 8] = *(const uint4*)(A + (size_t)(row0 + lr) * DIMC + kt + lk + 8);
    *(uint4*)&Bs[lr][lk]     = ld8_to_bf(Wp, (size_t)(col0 + lr) * DIMC + kt + lk, bf);
    *(uint4*)&Bs[lr][lk + 8] = ld8_to_bf(Wp, (size_t)(col0 + lr) * DIMC + kt + lk + 8, bf);
    __syncthreads();
    s16x8 af[4], bfr[4];
#pragma unroll
    for (int i = 0; i < 4; ++i)
      af[i] = *(const s16x8*)&As[(wr << 6) + (i << 4) + l15][quad << 3];
#pragma unroll
    for (int j = 0; j < 4; ++j)
      bfr[j] = *(const s16x8*)&Bs[(wc << 6) + (j << 4) + l15][quad << 3];
#pragma unroll
    for (int i = 0; i < 4; ++i)
#pragma unroll
      for (int j = 0; j < 4; ++j)
        acc[i][j] = MFMA16(af[i], bfr[j], acc[i][j]);
  }

#pragma unroll
  for (int jt = 0; jt < 4; ++jt) {
    int col = col0 + (wc << 6) + (jt << 4) + l15;
    float bv = ld1(Bp, col, bf);
#pragma unroll
    for (int i = 0; i < 4; ++i)
#pragma unroll
      for (int r = 0; r < 4; ++r) {
        int mrow = row0 + (wr << 6) + (i << 4) + (quad << 2) + r;
        float val = acc[i][jt][r] + bv;
        size_t off = (size_t)mrow * DIMC + col;
        if (bf) ((u16*)Out)[off] = f2bf(val);
        else    ((float*)Out)[off] = val;
      }
  }
}

// ---------------------------------------------------------------------------
extern "C" void kernel_launch(void* const* d_in, const int* in_sizes, int n_in,
                              void* d_out, int out_size, void* d_ws, size_t ws_size,
                              hipStream_t stream)
{
  const void* x    = d_in[0];   // (2,48,48,768)
  const void* rph  = d_in[1];   // (95,64)
  const void* rpw  = d_in[2];   // (95,64)
  const void* qkvw = d_in[3];   // (2304,768)
  const void* qkvb = d_in[4];   // (2304,)
  const void* pw   = d_in[5];   // (768,768)
  const void* pb   = d_in[6];   // (768,)

  // Workspace: [mode 16B] q,k bf16 (24,2304,64); vt bf16 (24,64,2304);
  // aout bf16 (2,2304,768); then split-K partials (f32) if room.
  int* mode = (int*)d_ws;
  const size_t qkv_elems = (size_t)HEADS * NQ * HD;   // 3,538,944
  u16* q    = (u16*)((char*)d_ws + 16);
  u16* k    = q + qkv_elems;
  u16* vt   = k + qkv_elems;
  u16* aout = vt + qkv_elems;
  const size_t base = 16 + 4 * qkv_elems * 2;         // 28,311,568 B
  const size_t perO = (size_t)HEADS * NQ * HD * 4;    // 14,155,776 B
  const size_t perL = (size_t)HEADS * NQ * 4;         //    221,184 B

  int S = 1;
  if (ws_size >= base + 3 * (perO + perL)) S = 3;
  else if (ws_size >= base + 2 * (perO + perL)) S = 2;
  float* opart = (float*)((char*)d_ws + base);
  float* lpart = (float*)((char*)d_ws + base + (size_t)S * perO);

  detect_k<<<1, 64, 0, stream>>>((const u16*)x, mode);
  qkv_gemm_k<<<dim3(18, 36), 256, 0, stream>>>(x, qkvw, qkvb, mode, q, k, vt);
  attn_k<<<dim3(864 * S), 256, 0, stream>>>(q, k, vt, rph, rpw, mode,
                                            S, opart, lpart, aout);
  if (S > 1)
    combine_k<<<dim3(3456), 256, 0, stream>>>(opart, lpart, S, aout);
  proj_gemm_k<<<dim3(6, 36), 256, 0, stream>>>(aout, pw, pb, mode, d_out);
}

// Round 6
// 645.869 us; speedup vs baseline: 1.3367x; 1.3367x over previous
//
#include <hip/hip_runtime.h>
#include <hip/hip_bf16.h>
#include <stdint.h>

// Problem constants
#define NQ    2304          // H*W = 48*48 tokens
#define MROWS 4608          // B*NQ
#define DIMC  768
#define NHEAD 12
#define HEADS 24            // B*NH
#define HD    64

typedef unsigned int uint;
typedef unsigned short u16;
typedef __attribute__((ext_vector_type(8))) short s16x8;   // 8 bf16 = 4 VGPR
typedef __attribute__((ext_vector_type(4))) float f32x4;   // mfma acc

#define MFMA16(a, b, c) __builtin_amdgcn_mfma_f32_16x16x32_bf16((a), (b), (c), 0, 0, 0)

static __device__ __forceinline__ float bfbits2f(uint u) {
  union { uint i; float f; } c; c.i = u << 16; return c.f;
}
static __device__ __forceinline__ u16 f2bf(float f) {
  __hip_bfloat16 h = __float2bfloat16(f);
  union { __hip_bfloat16 h; u16 u; } c; c.h = h; return c.u;
}
static __device__ __forceinline__ u16 f2h(float f) {
  union { _Float16 h; u16 u; } c; c.h = (_Float16)f; return c.u;
}
static __device__ __forceinline__ float h2f(u16 u) {
  union { u16 u; _Float16 h; } c; c.u = u; return (float)c.h;
}
static __device__ __forceinline__ void dec8(uint4 p, float* f) {
  f[0] = bfbits2f(p.x & 0xFFFFu); f[1] = bfbits2f(p.x >> 16);
  f[2] = bfbits2f(p.y & 0xFFFFu); f[3] = bfbits2f(p.y >> 16);
  f[4] = bfbits2f(p.z & 0xFFFFu); f[5] = bfbits2f(p.z >> 16);
  f[6] = bfbits2f(p.w & 0xFFFFu); f[7] = bfbits2f(p.w >> 16);
}
// dual-dtype 8-element load -> fp32 (bf=1: bf16, bf=0: fp32)
static __device__ __forceinline__ void ld8(const void* p, size_t idx, int bf, float* f) {
  if (bf) { dec8(*(const uint4*)((const u16*)p + idx), f); }
  else {
    const float4* q = (const float4*)((const float*)p + idx);
    float4 a = q[0], b = q[1];
    f[0] = a.x; f[1] = a.y; f[2] = a.z; f[3] = a.w;
    f[4] = b.x; f[5] = b.y; f[6] = b.z; f[7] = b.w;
  }
}
static __device__ __forceinline__ float ld1(const void* p, size_t idx, int bf) {
  return bf ? bfbits2f(((const u16*)p)[idx]) : ((const float*)p)[idx];
}
// dual-dtype 8-element load -> packed bf16 (uint4)
static __device__ __forceinline__ uint4 ld8_to_bf(const void* p, size_t idx, int bf) {
  if (bf) return *(const uint4*)((const u16*)p + idx);
  float f[8]; ld8(p, idx, 0, f);
  uint4 u;
  u.x = (uint)f2bf(f[0]) | ((uint)f2bf(f[1]) << 16);
  u.y = (uint)f2bf(f[2]) | ((uint)f2bf(f[3]) << 16);
  u.z = (uint)f2bf(f[4]) | ((uint)f2bf(f[5]) << 16);
  u.w = (uint)f2bf(f[6]) | ((uint)f2bf(f[7]) << 16);
  return u;
}

// ---------------------------------------------------------------------------
// K0: dtype detector (unchanged — PASSED; do not touch).
// ---------------------------------------------------------------------------
__global__ __launch_bounds__(64) void detect_k(const u16* __restrict__ x,
                                               int* __restrict__ mode) {
  int t = threadIdx.x;
  int cnt = 0;
  for (int i = 0; i < 32; ++i) {
    uint u = x[(size_t)(t * 32 + i) * 2];
    uint e = (u >> 7) & 0xFFu;
    uint mag = u & 0x7FFFu;
    if (mag == 0 || (e >= 113 && e <= 133)) cnt++;
  }
#pragma unroll
  for (int d = 1; d < 64; d <<= 1) cnt += __shfl_xor(cnt, d);
  if (t == 0) mode[0] = (cnt > 1024) ? 1 : 0;
}

// ---------------------------------------------------------------------------
// K1: QKV projection, MFMA.  V stored TRANSPOSED: Vt[(bh*HD + d)*NQ + n]
// so attn loads V^T B-frags directly from global. Q/K row-major. (unchanged)
// ---------------------------------------------------------------------------
__global__ __launch_bounds__(256) void qkv_gemm_k(
    const void* __restrict__ Xp, const void* __restrict__ Wp,
    const void* __restrict__ Bq, const int* __restrict__ mode,
    u16* __restrict__ Q, u16* __restrict__ K, u16* __restrict__ Vt)
{
  __shared__ __align__(16) u16 As[128][40];
  __shared__ __align__(16) u16 Bs[128][40];
  const int bf = mode[0];
  const int t = threadIdx.x;
  const int w = t >> 6, l15 = t & 15, quad = (t >> 4) & 3;
  const int wr = w >> 1, wc = w & 1;
  const int row0 = blockIdx.y << 7, col0 = blockIdx.x << 7;
  const int lr = t >> 1, lk = (t & 1) << 4;

  f32x4 zero4 = {0.f, 0.f, 0.f, 0.f};
  f32x4 acc[4][4];
#pragma unroll
  for (int i = 0; i < 4; ++i)
#pragma unroll
    for (int j = 0; j < 4; ++j) acc[i][j] = zero4;

  for (int kt = 0; kt < DIMC; kt += 32) {
    __syncthreads();
    *(uint4*)&As[lr][lk]     = ld8_to_bf(Xp, (size_t)(row0 + lr) * DIMC + kt + lk, bf);
    *(uint4*)&As[lr][lk + 8] = ld8_to_bf(Xp, (size_t)(row0 + lr) * DIMC + kt + lk + 8, bf);
    *(uint4*)&Bs[lr][lk]     = ld8_to_bf(Wp, (size_t)(col0 + lr) * DIMC + kt + lk, bf);
    *(uint4*)&Bs[lr][lk + 8] = ld8_to_bf(Wp, (size_t)(col0 + lr) * DIMC + kt + lk + 8, bf);
    __syncthreads();
    s16x8 af[4], bfr[4];
#pragma unroll
    for (int i = 0; i < 4; ++i)
      af[i] = *(const s16x8*)&As[(wr << 6) + (i << 4) + l15][quad << 3];
#pragma unroll
    for (int j = 0; j < 4; ++j)
      bfr[j] = *(const s16x8*)&Bs[(wc << 6) + (j << 4) + l15][quad << 3];
#pragma unroll
    for (int i = 0; i < 4; ++i)
#pragma unroll
      for (int j = 0; j < 4; ++j)
        acc[i][j] = MFMA16(af[i], bfr[j], acc[i][j]);
  }

#pragma unroll
  for (int jt = 0; jt < 4; ++jt) {
    int col = col0 + (wc << 6) + (jt << 4) + l15;     // 0..2303
    int which = col / DIMC;
    int rem = col - which * DIMC;
    int head = rem >> 6, d = rem & 63;
    float bv = ld1(Bq, col, bf);
#pragma unroll
    for (int i = 0; i < 4; ++i)
#pragma unroll
      for (int r = 0; r < 4; ++r) {
        int mrow = row0 + (wr << 6) + (i << 4) + (quad << 2) + r;
        int b_ = (mrow >= NQ) ? 1 : 0;
        int n = mrow - b_ * NQ;
        u16 val = f2bf(acc[i][jt][r] + bv);
        size_t bh = (size_t)(b_ * NHEAD + head);
        if (which == 2)      Vt[(bh * HD + d) * NQ + n] = val;     // transposed
        else if (which == 1) K[(bh * NQ + n) * HD + d] = val;
        else                 Q[(bh * NQ + n) * HD + d] = val;
      }
  }
}

// ---------------------------------------------------------------------------
// K1b: bias precompute (NEW, round 6).  Hoists the per-attn-block prologue
// (measured ~100-150 µs of r4's attn time; tripled by r5's split-K) into one
// embarrassingly-parallel pass.  Bh_g[bh][c][n] = q[bh,n,:].rel_h[qh(n)-c+47]
// Bw_g[bh][c][n] = q[bh,n,:].rel_w[qw(n)-c+47]   (fp16; proven precision in
// rounds 0-2, absmax unchanged).  Grid: 864 blocks = (bh, 64-row tile).
// ---------------------------------------------------------------------------
__global__ __launch_bounds__(256) void bias_k(
    const u16* __restrict__ Qw,
    const void* __restrict__ rph, const void* __restrict__ rpw,
    const int* __restrict__ mode,
    u16* __restrict__ Bh_g, u16* __restrict__ Bw_g)
{
  const int bf = mode[0];
  const int blk = blockIdx.x;           // 0..863
  const int bhd = blk / 36;
  const int qt = blk - bhd * 36;
  const int t = threadIdx.x;
  const int r = t >> 2, quad = t & 3;
  const int n = (qt << 6) + r;
  const int qh = (n * 10923) >> 19;     // n/48
  const int qw_ = n - qh * 48;
  const u16* qr = Qw + ((size_t)bhd * NQ + n) * HD;
  float fq[64];
#pragma unroll
  for (int v8 = 0; v8 < 8; ++v8) dec8(*(const uint4*)(qr + (v8 << 3)), &fq[v8 << 3]);
#pragma unroll
  for (int it = 0; it < 12; ++it) {
    int c = (it << 2) + quad;           // 0..47
    size_t ih = (size_t)(qh - c + 47) * HD;
    size_t iw = (size_t)(qw_ - c + 47) * HD;
    float sh = 0.f, sw = 0.f;
#pragma unroll
    for (int v8 = 0; v8 < 8; ++v8) {
      float fh[8], fw[8];
      ld8(rph, ih + (v8 << 3), bf, fh);
      ld8(rpw, iw + (v8 << 3), bf, fw);
#pragma unroll
      for (int j = 0; j < 8; ++j) { sh += fq[(v8 << 3) + j] * fh[j]; sw += fq[(v8 << 3) + j] * fw[j]; }
    }
    Bh_g[((size_t)bhd * 48 + c) * NQ + n] = f2h(sh);
    Bw_g[((size_t)bhd * 48 + c) * NQ + n] = f2h(sw);
  }
}

// ---------------------------------------------------------------------------
// K2: MFMA flash attention, round 6.
//  - bias prologue GONE: block loads its 64x48 fp16 slices of the
//    precomputed tables into LDS (coalesced; converts to f32).
//  - split-K S=2 (r5 path, numerically verified) now that its per-block
//    prologue cost is gone.  S=1 fallback.
//  - main loop: barrier-free, direct-global K/V (L2-resident via XCD
//    head-grouping), no-max softmax, shfl P-exchange.  Same as r5.
//  LDS: BhL 48x64 f32 (12 KB) + BwL 64x52 f32 (13.3 KB) = 25.3 KB.
// ---------------------------------------------------------------------------
__global__ __launch_bounds__(256) void attn_k(
    const u16* __restrict__ Qw, const u16* __restrict__ Kw,
    const u16* __restrict__ Vtg,
    const u16* __restrict__ Bh_g, const u16* __restrict__ Bw_g,
    int S, float* __restrict__ Opart, float* __restrict__ Lpart,
    u16* __restrict__ Aout)
{
  __shared__ __align__(16) float BhL[48][64];   // [kh][local qrow]
  __shared__ __align__(16) float BwL[64][52];   // [local qrow][kw]

  // XCD swizzle: nwg = 864*S (div by 8). XCD x runs heads 3x..3x+2 only ->
  // per-XCD K/V working set 1.76 MB -> L2-resident.
  const int bid = blockIdx.x;
  const int xcd = bid & 7;
  const int local = bid >> 3;            // [0, 108*S)
  const int per_head = 36 * S;
  const int head_l = local / per_head;   // 0..2
  const int rem = local - head_l * per_head;
  int qb, z;
  if (S == 2) { qb = rem >> 1; z = rem & 1; }
  else        { qb = rem;      z = 0; }
  const int bhd = xcd * 3 + head_l;
  const int q0 = qb << 6;
  const int span = NQ / S;               // 2304 or 1152 (multiples of 48&64)
  const int kt_lo = z * span, kt_hi = kt_lo + span;

  const int t = threadIdx.x;
  const int w = t >> 6, l15 = t & 15, quad = (t >> 4) & 3;
  const float scale = 0.125f;   // 64^-0.5

  const u16* kbase  = Kw  + (size_t)bhd * NQ * HD;
  const u16* vtbase = Vtg + (size_t)bhd * HD * NQ;
  const int q0w = q0 + (w << 4);
  const int qrl = (w << 4) + l15;        // this lane's local q row

  // ---- LDS fill from precomputed tables (coalesced fp16 reads, 12 iters)
  for (int e = t; e < 48 * 64; e += 256) {
    int c = e >> 6, r = e & 63;
    size_t gi = ((size_t)bhd * 48 + c) * NQ + q0 + r;
    BhL[c][r] = h2f(Bh_g[gi]);
    BwL[r][c] = h2f(Bw_g[gi]);
  }

  // Q B-frags (loop-invariant): B[n=qrow=l15][k=quad*8+j]
  const u16* qfrag = Qw + ((size_t)bhd * NQ + q0w + l15) * HD + (quad << 3);
  s16x8 qa0 = *(const s16x8*)(qfrag);
  s16x8 qa1 = *(const s16x8*)(qfrag + 32);

  __syncthreads();   // bias tables visible

  f32x4 zero4 = {0.f, 0.f, 0.f, 0.f};
  f32x4 acc_o[4];
#pragma unroll
  for (int nc = 0; nc < 4; ++nc) acc_o[nc] = zero4;
  float l_st = 0.f;   // lane-local partial sum of exp(S); reduced in epilogue
  int km = 0;         // kt0 % 48; kt_lo % 48 == 0 for all splits

  for (int kt0 = kt_lo; kt0 < kt_hi; kt0 += 64) {
    // S^T = K Q^T : lane holds S[key = kt0+16*nc+4*quad+r][qrow = qrl]
    f32x4 acc_s[4];
#pragma unroll
    for (int nc = 0; nc < 4; ++nc) {
      const u16* kp = kbase + (size_t)(kt0 + (nc << 4) + l15) * HD + (quad << 3);
      s16x8 kb0 = *(const s16x8*)(kp);
      s16x8 kb1 = *(const s16x8*)(kp + 32);
      f32x4 a = MFMA16(kb0, qa0, zero4);
      acc_s[nc] = MFMA16(kb1, qa1, a);
    }

    // V^T frag loads (half 0) issued now; latency flies under softmax VALU
    s16x8 vb0[4];
#pragma unroll
    for (int nc = 0; nc < 4; ++nc) {
      const u16* vp = vtbase + (size_t)((nc << 4) + l15) * NQ + kt0 + (quad << 3);
      vb0[nc] = *(const s16x8*)(vp);
    }

    // bias reads: Bh 2 scalars; Bw 4 x b128 (4 consecutive kw per nc-group)
    int kh0 = (kt0 * 10923) >> 19;
    float bh0v = BhL[kh0][qrl];
    float bh1v = BhL[kh0 + 1][qrl];          // kh0 <= 46 always
    int thr = (kh0 + 1) * 48 - kt0;          // local key >= thr -> kh0+1
    f32x4 bwv[4];
#pragma unroll
    for (int nc = 0; nc < 4; ++nc) {
      int bnc = km + (nc << 4);
      bnc = (bnc >= 48) ? bnc - 48 : bnc;    // in {0,16,32}; +4*quad+3 <= 47
      bwv[nc] = *(const f32x4*)&BwL[qrl][bnc + (quad << 2)];
    }

    // scale + bias -> exp (no max subtraction: scores bounded)
    float sv[16];
    float sum = 0.f;
#pragma unroll
    for (int nc = 0; nc < 4; ++nc)
#pragma unroll
      for (int r = 0; r < 4; ++r) {
        int kl = (nc << 4) + (quad << 2) + r;
        float s = acc_s[nc][r] * scale + ((kl >= thr) ? bh1v : bh0v) + bwv[nc][r];
        s = __expf(s);
        sv[(nc << 2) + r] = s;
        sum += s;
      }
    l_st += sum;

    // P -> A-frags via cross-quad shfl exchange (two key-halves).
    // A[m=l15(qrow)][k=quad*8+j (key)].
    int srcA = ((quad & 1) << 5) + l15;   // source quad 2*(quad&1)
    int srcB = srcA + 16;                 // source quad 2*(quad&1)+1
    int hi = quad >> 1;
    // half 0: keys kt0+0..31
    {
      uint W0 = (uint)f2bf(sv[0]) | ((uint)f2bf(sv[1]) << 16);
      uint W1 = (uint)f2bf(sv[2]) | ((uint)f2bf(sv[3]) << 16);
      uint W2 = (uint)f2bf(sv[4]) | ((uint)f2bf(sv[5]) << 16);
      uint W3 = (uint)f2bf(sv[6]) | ((uint)f2bf(sv[7]) << 16);
      union { uint u[4]; s16x8 v; } pf;
      uint e0 = __shfl(W0, srcA), e1 = __shfl(W1, srcA), e2 = __shfl(W2, srcA), e3 = __shfl(W3, srcA);
      pf.u[0] = hi ? e2 : e0; pf.u[1] = hi ? e3 : e1;
      uint g0 = __shfl(W0, srcB), g1 = __shfl(W1, srcB), g2 = __shfl(W2, srcB), g3 = __shfl(W3, srcB);
      pf.u[2] = hi ? g2 : g0; pf.u[3] = hi ? g3 : g1;
#pragma unroll
      for (int nc = 0; nc < 4; ++nc)
        acc_o[nc] = MFMA16(pf.v, vb0[nc], acc_o[nc]);
    }
    // half 1: keys kt0+32..63 (V loads issued here, hidden by half-0 MFMAs)
    {
      s16x8 vb1[4];
#pragma unroll
      for (int nc = 0; nc < 4; ++nc) {
        const u16* vp = vtbase + (size_t)((nc << 4) + l15) * NQ + kt0 + 32 + (quad << 3);
        vb1[nc] = *(const s16x8*)(vp);
      }
      uint W4 = (uint)f2bf(sv[8])  | ((uint)f2bf(sv[9])  << 16);
      uint W5 = (uint)f2bf(sv[10]) | ((uint)f2bf(sv[11]) << 16);
      uint W6 = (uint)f2bf(sv[12]) | ((uint)f2bf(sv[13]) << 16);
      uint W7 = (uint)f2bf(sv[14]) | ((uint)f2bf(sv[15]) << 16);
      union { uint u[4]; s16x8 v; } pf;
      uint e0 = __shfl(W4, srcA), e1 = __shfl(W5, srcA), e2 = __shfl(W6, srcA), e3 = __shfl(W7, srcA);
      pf.u[0] = hi ? e2 : e0; pf.u[1] = hi ? e3 : e1;
      uint g0 = __shfl(W4, srcB), g1 = __shfl(W5, srcB), g2 = __shfl(W6, srcB), g3 = __shfl(W7, srcB);
      pf.u[2] = hi ? g2 : g0; pf.u[3] = hi ? g3 : g1;
#pragma unroll
      for (int nc = 0; nc < 4; ++nc)
        acc_o[nc] = MFMA16(pf.v, vb1[nc], acc_o[nc]);
    }
    km += 16;
    if (km >= 48) km -= 48;
  }

  // reduce l across quads (each lane then has full sum for qrow = q0w+l15)
  l_st += __shfl_xor(l_st, 16);
  l_st += __shfl_xor(l_st, 32);

  if (S > 1) {
    // partial path: unnormalized f32 O + l per split
    float* Op = Opart + ((size_t)(z * HEADS + bhd) * NQ + q0) * HD;
#pragma unroll
    for (int r = 0; r < 4; ++r) {
      int row = (w << 4) + (quad << 2) + r;
#pragma unroll
      for (int nc = 0; nc < 4; ++nc)
        Op[(size_t)row * HD + (nc << 4) + l15] = acc_o[nc][r];
    }
    if (quad == 0)
      Lpart[(size_t)(z * HEADS + bhd) * NQ + q0w + l15] = l_st;
  } else {
    // direct path: divide by l (broadcast from lane l15 == 4*quad+r), store bf16
    int b_ = bhd / NHEAD, head = bhd - b_ * NHEAD;
    float invl = 1.f / l_st;
    int bsrc = (quad << 4) + (quad << 2);
#pragma unroll
    for (int r = 0; r < 4; ++r) {
      float inv = __shfl(invl, bsrc + r);
      int token = q0 + (w << 4) + (quad << 2) + r;
      u16* dst = Aout + ((size_t)b_ * NQ + token) * DIMC + (head << 6);
#pragma unroll
      for (int nc = 0; nc < 4; ++nc)
        dst[(nc << 4) + l15] = f2bf(acc_o[nc][r] * inv);
    }
  }
}

// ---------------------------------------------------------------------------
// K2b: combine split-K partials: O = (sum_z O_z) / (sum_z l_z), store bf16
// into aout (b, token, head*64+d). Grid: 884736 threads, 4 f32 each.
// ---------------------------------------------------------------------------
__global__ __launch_bounds__(256) void combine_k(
    const float* __restrict__ Op, const float* __restrict__ Lp,
    int S, u16* __restrict__ Aout)
{
  int idx = blockIdx.x * 256 + threadIdx.x;   // 0 .. 884735
  int m = idx / 192;                          // row 0..4607 (DIMC/4 = 192)
  int cq = idx - m * 192;
  int ccol = cq << 2;                         // col of first of 4
  int head = ccol >> 6, d0 = ccol & 63;
  int b_ = (m >= NQ) ? 1 : 0;
  int n = m - b_ * NQ;
  int bh = b_ * NHEAD + head;
  float ox = 0.f, oy = 0.f, oz = 0.f, ow = 0.f, ls = 0.f;
  for (int zz = 0; zz < S; ++zz) {
    const float* ob = Op + ((size_t)(zz * HEADS + bh) * NQ + n) * HD + d0;
    float4 v = *(const float4*)ob;
    ox += v.x; oy += v.y; oz += v.z; ow += v.w;
    ls += Lp[(size_t)(zz * HEADS + bh) * NQ + n];
  }
  float inv = 1.f / ls;
  u16* dst = Aout + (size_t)m * DIMC + ccol;
  dst[0] = f2bf(ox * inv); dst[1] = f2bf(oy * inv);
  dst[2] = f2bf(oz * inv); dst[3] = f2bf(ow * inv);
}

// ---------------------------------------------------------------------------
// K3: output projection, MFMA (unchanged).
// ---------------------------------------------------------------------------
__global__ __launch_bounds__(256) void proj_gemm_k(
    const u16* __restrict__ A, const void* __restrict__ Wp,
    const void* __restrict__ Bp, const int* __restrict__ mode,
    void* __restrict__ Out)
{
  __shared__ __align__(16) u16 As[128][40];
  __shared__ __align__(16) u16 Bs[128][40];
  const int bf = mode[0];
  const int t = threadIdx.x;
  const int w = t >> 6, l15 = t & 15, quad = (t >> 4) & 3;
  const int wr = w >> 1, wc = w & 1;
  const int row0 = blockIdx.y << 7, col0 = blockIdx.x << 7;
  const int lr = t >> 1, lk = (t & 1) << 4;

  f32x4 zero4 = {0.f, 0.f, 0.f, 0.f};
  f32x4 acc[4][4];
#pragma unroll
  for (int i = 0; i < 4; ++i)
#pragma unroll
    for (int j = 0; j < 4; ++j) acc[i][j] = zero4;

  for (int kt = 0; kt < DIMC; kt += 32) {
    __syncthreads();
    *(uint4*)&As[lr][lk]     = *(const uint4*)(A + (size_t)(row0 + lr) * DIMC + kt + lk);
    *(uint4*)&As[lr][lk + 8] = *(const uint4*)(A + (size_t)(row0 + lr) * DIMC + kt + lk + 8);
    *(uint4*)&Bs[lr][lk]     = ld8_to_bf(Wp, (size_t)(col0 + lr) * DIMC + kt + lk, bf);
    *(uint4*)&Bs[lr][lk + 8] = ld8_to_bf(Wp, (size_t)(col0 + lr) * DIMC + kt + lk + 8, bf);
    __syncthreads();
    s16x8 af[4], bfr[4];
#pragma unroll
    for (int i = 0; i < 4; ++i)
      af[i] = *(const s16x8*)&As[(wr << 6) + (i << 4) + l15][quad << 3];
#pragma unroll
    for (int j = 0; j < 4; ++j)
      bfr[j] = *(const s16x8*)&Bs[(wc << 6) + (j << 4) + l15][quad << 3];
#pragma unroll
    for (int i = 0; i < 4; ++i)
#pragma unroll
      for (int j = 0; j < 4; ++j)
        acc[i][j] = MFMA16(af[i], bfr[j], acc[i][j]);
  }

#pragma unroll
  for (int jt = 0; jt < 4; ++jt) {
    int col = col0 + (wc << 6) + (jt << 4) + l15;
    float bv = ld1(Bp, col, bf);
#pragma unroll
    for (int i = 0; i < 4; ++i)
#pragma unroll
      for (int r = 0; r < 4; ++r) {
        int mrow = row0 + (wr << 6) + (i << 4) + (quad << 2) + r;
        float val = acc[i][jt][r] + bv;
        size_t off = (size_t)mrow * DIMC + col;
        if (bf) ((u16*)Out)[off] = f2bf(val);
        else    ((float*)Out)[off] = val;
      }
  }
}

// ---------------------------------------------------------------------------
extern "C" void kernel_launch(void* const* d_in, const int* in_sizes, int n_in,
                              void* d_out, int out_size, void* d_ws, size_t ws_size,
                              hipStream_t stream)
{
  const void* x    = d_in[0];   // (2,48,48,768)
  const void* rph  = d_in[1];   // (95,64)
  const void* rpw  = d_in[2];   // (95,64)
  const void* qkvw = d_in[3];   // (2304,768)
  const void* qkvb = d_in[4];   // (2304,)
  const void* pw   = d_in[5];   // (768,768)
  const void* pb   = d_in[6];   // (768,)

  // Workspace layout:
  //  [mode 16B] q,k bf16 (24,2304,64); vt bf16 (24,64,2304); aout bf16
  //  (2,2304,768)  -> base = 28,311,568 B
  //  bias tables fp16 (24,48,2304) x2   -> +10,616,832 B
  //  split-K partials f32 (S x O + S x l) if room.
  int* mode = (int*)d_ws;
  const size_t qkv_elems = (size_t)HEADS * NQ * HD;   // 3,538,944
  u16* q    = (u16*)((char*)d_ws + 16);
  u16* k    = q + qkv_elems;
  u16* vt   = k + qkv_elems;
  u16* aout = vt + qkv_elems;
  const size_t base = 16 + 4 * qkv_elems * 2;         // 28,311,568 B
  const size_t biasElems = (size_t)HEADS * 48 * NQ;   // 2,654,208 per table
  u16* bh_g = (u16*)((char*)d_ws + base);
  u16* bw_g = bh_g + biasElems;
  const size_t base2 = base + 2 * biasElems * 2;      // +10,616,832 B
  const size_t perO = (size_t)HEADS * NQ * HD * 4;    // 14,155,776 B
  const size_t perL = (size_t)HEADS * NQ * 4;         //    221,184 B

  int S = 1;
  if (ws_size >= base2 + 2 * (perO + perL)) S = 2;
  float* opart = (float*)((char*)d_ws + base2);
  float* lpart = (float*)((char*)d_ws + base2 + (size_t)S * perO);

  detect_k<<<1, 64, 0, stream>>>((const u16*)x, mode);
  qkv_gemm_k<<<dim3(18, 36), 256, 0, stream>>>(x, qkvw, qkvb, mode, q, k, vt);
  bias_k<<<dim3(864), 256, 0, stream>>>(q, rph, rpw, mode, bh_g, bw_g);
  attn_k<<<dim3(864 * S), 256, 0, stream>>>(q, k, vt, bh_g, bw_g,
                                            S, opart, lpart, aout);
  if (S > 1)
    combine_k<<<dim3(3456), 256, 0, stream>>>(opart, lpart, S, aout);
  proj_gemm_k<<<dim3(6, 36), 256, 0, stream>>>(aout, pw, pb, mode, d_out);
}

// Round 7
// 484.746 us; speedup vs baseline: 1.7810x; 1.3324x over previous
//
#include <hip/hip_runtime.h>
#include <hip/hip_bf16.h>
#include <stdint.h>

// Problem constants
#define NQ    2304          // H*W = 48*48 tokens
#define MROWS 4608          // B*NQ
#define DIMC  768
#define NHEAD 12
#define HEADS 24            // B*NH
#define HD    64

typedef unsigned int uint;
typedef unsigned short u16;
typedef __attribute__((ext_vector_type(8))) short s16x8;   // 8 bf16 = 4 VGPR
typedef __attribute__((ext_vector_type(4))) float f32x4;   // mfma acc

#define MFMA16(a, b, c) __builtin_amdgcn_mfma_f32_16x16x32_bf16((a), (b), (c), 0, 0, 0)

static __device__ __forceinline__ float bfbits2f(uint u) {
  union { uint i; float f; } c; c.i = u << 16; return c.f;
}
static __device__ __forceinline__ u16 f2bf(float f) {
  __hip_bfloat16 h = __float2bfloat16(f);
  union { __hip_bfloat16 h; u16 u; } c; c.h = h; return c.u;
}
static __device__ __forceinline__ u16 f2h(float f) {
  union { _Float16 h; u16 u; } c; c.h = (_Float16)f; return c.u;
}
static __device__ __forceinline__ float h2f(u16 u) {
  union { u16 u; _Float16 h; } c; c.u = u; return (float)c.h;
}
static __device__ __forceinline__ void dec8(uint4 p, float* f) {
  f[0] = bfbits2f(p.x & 0xFFFFu); f[1] = bfbits2f(p.x >> 16);
  f[2] = bfbits2f(p.y & 0xFFFFu); f[3] = bfbits2f(p.y >> 16);
  f[4] = bfbits2f(p.z & 0xFFFFu); f[5] = bfbits2f(p.z >> 16);
  f[6] = bfbits2f(p.w & 0xFFFFu); f[7] = bfbits2f(p.w >> 16);
}
// dual-dtype 8-element load -> fp32 (bf=1: bf16, bf=0: fp32)
static __device__ __forceinline__ void ld8(const void* p, size_t idx, int bf, float* f) {
  if (bf) { dec8(*(const uint4*)((const u16*)p + idx), f); }
  else {
    const float4* q = (const float4*)((const float*)p + idx);
    float4 a = q[0], b = q[1];
    f[0] = a.x; f[1] = a.y; f[2] = a.z; f[3] = a.w;
    f[4] = b.x; f[5] = b.y; f[6] = b.z; f[7] = b.w;
  }
}
static __device__ __forceinline__ float ld1(const void* p, size_t idx, int bf) {
  return bf ? bfbits2f(((const u16*)p)[idx]) : ((const float*)p)[idx];
}
// dual-dtype 8-element load -> packed bf16 (uint4)
static __device__ __forceinline__ uint4 ld8_to_bf(const void* p, size_t idx, int bf) {
  if (bf) return *(const uint4*)((const u16*)p + idx);
  float f[8]; ld8(p, idx, 0, f);
  uint4 u;
  u.x = (uint)f2bf(f[0]) | ((uint)f2bf(f[1]) << 16);
  u.y = (uint)f2bf(f[2]) | ((uint)f2bf(f[3]) << 16);
  u.z = (uint)f2bf(f[4]) | ((uint)f2bf(f[5]) << 16);
  u.w = (uint)f2bf(f[6]) | ((uint)f2bf(f[7]) << 16);
  return u;
}

// ---------------------------------------------------------------------------
// K0: dtype detector (unchanged — PASSED; do not touch).
// ---------------------------------------------------------------------------
__global__ __launch_bounds__(64) void detect_k(const u16* __restrict__ x,
                                               int* __restrict__ mode) {
  int t = threadIdx.x;
  int cnt = 0;
  for (int i = 0; i < 32; ++i) {
    uint u = x[(size_t)(t * 32 + i) * 2];
    uint e = (u >> 7) & 0xFFu;
    uint mag = u & 0x7FFFu;
    if (mag == 0 || (e >= 113 && e <= 133)) cnt++;
  }
#pragma unroll
  for (int d = 1; d < 64; d <<= 1) cnt += __shfl_xor(cnt, d);
  if (t == 0) mode[0] = (cnt > 1024) ? 1 : 0;
}

// ---------------------------------------------------------------------------
// K1: QKV projection, MFMA.  V stored TRANSPOSED: Vt[(bh*HD + d)*NQ + n]
// so attn loads V^T B-frags directly from global. Q/K row-major. (unchanged)
// ---------------------------------------------------------------------------
__global__ __launch_bounds__(256) void qkv_gemm_k(
    const void* __restrict__ Xp, const void* __restrict__ Wp,
    const void* __restrict__ Bq, const int* __restrict__ mode,
    u16* __restrict__ Q, u16* __restrict__ K, u16* __restrict__ Vt)
{
  __shared__ __align__(16) u16 As[128][40];
  __shared__ __align__(16) u16 Bs[128][40];
  const int bf = mode[0];
  const int t = threadIdx.x;
  const int w = t >> 6, l15 = t & 15, quad = (t >> 4) & 3;
  const int wr = w >> 1, wc = w & 1;
  const int row0 = blockIdx.y << 7, col0 = blockIdx.x << 7;
  const int lr = t >> 1, lk = (t & 1) << 4;

  f32x4 zero4 = {0.f, 0.f, 0.f, 0.f};
  f32x4 acc[4][4];
#pragma unroll
  for (int i = 0; i < 4; ++i)
#pragma unroll
    for (int j = 0; j < 4; ++j) acc[i][j] = zero4;

  for (int kt = 0; kt < DIMC; kt += 32) {
    __syncthreads();
    *(uint4*)&As[lr][lk]     = ld8_to_bf(Xp, (size_t)(row0 + lr) * DIMC + kt + lk, bf);
    *(uint4*)&As[lr][lk + 8] = ld8_to_bf(Xp, (size_t)(row0 + lr) * DIMC + kt + lk + 8, bf);
    *(uint4*)&Bs[lr][lk]     = ld8_to_bf(Wp, (size_t)(col0 + lr) * DIMC + kt + lk, bf);
    *(uint4*)&Bs[lr][lk + 8] = ld8_to_bf(Wp, (size_t)(col0 + lr) * DIMC + kt + lk + 8, bf);
    __syncthreads();
    s16x8 af[4], bfr[4];
#pragma unroll
    for (int i = 0; i < 4; ++i)
      af[i] = *(const s16x8*)&As[(wr << 6) + (i << 4) + l15][quad << 3];
#pragma unroll
    for (int j = 0; j < 4; ++j)
      bfr[j] = *(const s16x8*)&Bs[(wc << 6) + (j << 4) + l15][quad << 3];
#pragma unroll
    for (int i = 0; i < 4; ++i)
#pragma unroll
      for (int j = 0; j < 4; ++j)
        acc[i][j] = MFMA16(af[i], bfr[j], acc[i][j]);
  }

#pragma unroll
  for (int jt = 0; jt < 4; ++jt) {
    int col = col0 + (wc << 6) + (jt << 4) + l15;     // 0..2303
    int which = col / DIMC;
    int rem = col - which * DIMC;
    int head = rem >> 6, d = rem & 63;
    float bv = ld1(Bq, col, bf);
#pragma unroll
    for (int i = 0; i < 4; ++i)
#pragma unroll
      for (int r = 0; r < 4; ++r) {
        int mrow = row0 + (wr << 6) + (i << 4) + (quad << 2) + r;
        int b_ = (mrow >= NQ) ? 1 : 0;
        int n = mrow - b_ * NQ;
        u16 val = f2bf(acc[i][jt][r] + bv);
        size_t bh = (size_t)(b_ * NHEAD + head);
        if (which == 2)      Vt[(bh * HD + d) * NQ + n] = val;     // transposed
        else if (which == 1) K[(bh * NQ + n) * HD + d] = val;
        else                 Q[(bh * NQ + n) * HD + d] = val;
      }
  }
}

// ---------------------------------------------------------------------------
// K1b: bias precompute as MFMA GEMM (round 7; replaces the ~150 µs scalar
// bias_k).  T[n][j] = q[n]·rel[j] is a GEMM Q[2304x64] x rel^T[64x95] per
// head; Bh[n][c] = T[n][qh(n)+47-c] — each (n,j) scatters to exactly one c.
// Block: 128 rows of one head x 192 cols (rel_h at 0..94, rel_w at 96..190).
// K=64 fully LDS-resident (no k-loop staging). Grid 24*18 = 432 blocks.
// Output layout IDENTICAL to round-6 tables: fp16 [bh][c][n].
// ---------------------------------------------------------------------------
__global__ __launch_bounds__(256) void bias_gemm_k(
    const u16* __restrict__ Qw,
    const void* __restrict__ rph, const void* __restrict__ rpw,
    const int* __restrict__ mode,
    u16* __restrict__ Bh_g, u16* __restrict__ Bw_g)
{
  __shared__ __align__(16) u16 As[128][72];
  __shared__ __align__(16) u16 Bs[192][72];
  const int bf = mode[0];
  const int t = threadIdx.x;
  const int w = t >> 6, l15 = t & 15, quad = (t >> 4) & 3;
  const int wr = w >> 1, wc = w & 1;
  const int blk = blockIdx.x;          // 0..431
  const int bhd = blk / 18;
  const int row0 = (blk - bhd * 18) << 7;

  // stage A: 128 q-rows x 64 k (bf16 native, coalesced)
  {
    int lr = t >> 1, lk = (t & 1) << 5;
    const u16* src = Qw + ((size_t)bhd * NQ + row0 + lr) * HD + lk;
    *(uint4*)&As[lr][lk]      = *(const uint4*)(src);
    *(uint4*)&As[lr][lk + 8]  = *(const uint4*)(src + 8);
    *(uint4*)&As[lr][lk + 16] = *(const uint4*)(src + 16);
    *(uint4*)&As[lr][lk + 24] = *(const uint4*)(src + 24);
  }
  // stage B: rows 0..94 = rel_h, 96..190 = rel_w (pad rows clamped; their
  // output cols are discarded by the scatter predicate)
  for (int e = t; e < 384; e += 256) {
    int row = e >> 1, k32 = (e & 1) << 5;
    int tab = (row >= 96) ? 1 : 0;
    int r2 = row - (tab ? 96 : 0);
    if (r2 > 94) r2 = 0;
    const void* src = tab ? rpw : rph;
    *(uint4*)&Bs[row][k32]      = ld8_to_bf(src, (size_t)r2 * HD + k32, bf);
    *(uint4*)&Bs[row][k32 + 8]  = ld8_to_bf(src, (size_t)r2 * HD + k32 + 8, bf);
    *(uint4*)&Bs[row][k32 + 16] = ld8_to_bf(src, (size_t)r2 * HD + k32 + 16, bf);
    *(uint4*)&Bs[row][k32 + 24] = ld8_to_bf(src, (size_t)r2 * HD + k32 + 24, bf);
  }
  __syncthreads();

  f32x4 zero4 = {0.f, 0.f, 0.f, 0.f};
  f32x4 acc[4][6];
#pragma unroll
  for (int i = 0; i < 4; ++i)
#pragma unroll
    for (int j = 0; j < 6; ++j) acc[i][j] = zero4;

#pragma unroll
  for (int ks = 0; ks < 2; ++ks) {
    s16x8 af[4], bfr[6];
#pragma unroll
    for (int i = 0; i < 4; ++i)
      af[i] = *(const s16x8*)&As[(wr << 6) + (i << 4) + l15][(ks << 5) + (quad << 3)];
#pragma unroll
    for (int j = 0; j < 6; ++j)
      bfr[j] = *(const s16x8*)&Bs[wc * 96 + (j << 4) + l15][(ks << 5) + (quad << 3)];
#pragma unroll
    for (int i = 0; i < 4; ++i)
#pragma unroll
      for (int j = 0; j < 6; ++j)
        acc[i][j] = MFMA16(af[i], bfr[j], acc[i][j]);
  }

  // scatter epilogue: col j of table tab -> c = coord(n)+47-j  (0..47 valid)
#pragma unroll
  for (int jt = 0; jt < 6; ++jt) {
    int col = wc * 96 + (jt << 4) + l15;     // 0..191
    int tab = (col >= 96) ? 1 : 0;
    int j = col - (tab ? 96 : 0);
    if (j >= 95) continue;
    u16* dstT = tab ? Bw_g : Bh_g;
#pragma unroll
    for (int i = 0; i < 4; ++i)
#pragma unroll
      for (int r = 0; r < 4; ++r) {
        int n = row0 + (wr << 6) + (i << 4) + (quad << 2) + r;
        int qh = (n * 10923) >> 19;
        int coord = tab ? (n - qh * 48) : qh;
        int c = coord + 47 - j;
        if (c >= 0 && c < 48)
          dstT[((size_t)bhd * 48 + c) * NQ + n] = f2h(acc[i][jt][r]);
      }
  }
}

// ---------------------------------------------------------------------------
// K2: MFMA flash attention, round 7: K-fragment software prefetch.
//  r6 evidence: 35% occupancy but VALUBusy 20% -> each wave ~93% stalled on
//  the per-tile K loads (no cross-iteration pipelining). Fix: pair-unrolled
//  ping-pong (kbA/kbB, static indices only); next tile's 8 K-frags issued
//  right after current QK MFMAs -> ~500cy of softmax+PV hides their latency.
//  sv[16] eliminated (exp->pack fused into 8 W words) to offset +32 VGPR.
//  Rest (bias LDS tables, direct-global V^T, no-max softmax, split-K) = r6.
// ---------------------------------------------------------------------------
#define ATTN_TILE(KB, KN, PREF, T0, TN, KM) do {                              \
    f32x4 acc_s[4];                                                           \
    _Pragma("unroll")                                                         \
    for (int nc = 0; nc < 4; ++nc) {                                          \
      f32x4 a_ = MFMA16(KB[2*nc], qa0, zero4);                                \
      acc_s[nc] = MFMA16(KB[2*nc+1], qa1, a_);                                \
    }                                                                         \
    s16x8 vb0[4];                                                             \
    _Pragma("unroll")                                                         \
    for (int nc = 0; nc < 4; ++nc)                                            \
      vb0[nc] = *(const s16x8*)(vtbase + (size_t)((nc<<4)+l15)*NQ + (T0) + (quad<<3)); \
    if (PREF) {                                                               \
      _Pragma("unroll")                                                       \
      for (int nc = 0; nc < 4; ++nc) {                                        \
        const u16* kp_ = kbase + (size_t)((TN) + (nc<<4) + l15) * HD + (quad<<3); \
        KN[2*nc]   = *(const s16x8*)(kp_);                                    \
        KN[2*nc+1] = *(const s16x8*)(kp_ + 32);                               \
      }                                                                       \
    }                                                                         \
    int kh0_ = ((T0) * 10923) >> 19;                                          \
    float bh0v_ = BhL[kh0_][qrl];                                             \
    float bh1v_ = BhL[kh0_ + 1][qrl];                                         \
    int thr_ = (kh0_ + 1) * 48 - (T0);                                        \
    float sum_ = 0.f;                                                         \
    uint W[8];                                                                \
    _Pragma("unroll")                                                         \
    for (int nc = 0; nc < 4; ++nc) {                                          \
      int bnc_ = (KM) + (nc << 4); if (bnc_ >= 48) bnc_ -= 48;                \
      f32x4 bwv_ = *(const f32x4*)&BwL[qrl][bnc_ + (quad << 2)];              \
      float e0_, e1_, e2_, e3_;                                               \
      { int kl_=(nc<<4)+(quad<<2);   float s_=acc_s[nc][0]*scale+((kl_>=thr_)?bh1v_:bh0v_)+bwv_[0]; e0_=__expf(s_); } \
      { int kl_=(nc<<4)+(quad<<2)+1; float s_=acc_s[nc][1]*scale+((kl_>=thr_)?bh1v_:bh0v_)+bwv_[1]; e1_=__expf(s_); } \
      { int kl_=(nc<<4)+(quad<<2)+2; float s_=acc_s[nc][2]*scale+((kl_>=thr_)?bh1v_:bh0v_)+bwv_[2]; e2_=__expf(s_); } \
      { int kl_=(nc<<4)+(quad<<2)+3; float s_=acc_s[nc][3]*scale+((kl_>=thr_)?bh1v_:bh0v_)+bwv_[3]; e3_=__expf(s_); } \
      sum_ += (e0_ + e1_) + (e2_ + e3_);                                      \
      W[2*nc]   = (uint)f2bf(e0_) | ((uint)f2bf(e1_) << 16);                  \
      W[2*nc+1] = (uint)f2bf(e2_) | ((uint)f2bf(e3_) << 16);                  \
    }                                                                         \
    l_st += sum_;                                                             \
    s16x8 vb1[4];                                                             \
    _Pragma("unroll")                                                         \
    for (int nc = 0; nc < 4; ++nc)                                            \
      vb1[nc] = *(const s16x8*)(vtbase + (size_t)((nc<<4)+l15)*NQ + (T0) + 32 + (quad<<3)); \
    {                                                                         \
      uint e0 = __shfl(W[0], srcA), e1 = __shfl(W[1], srcA), e2 = __shfl(W[2], srcA), e3 = __shfl(W[3], srcA); \
      uint g0 = __shfl(W[0], srcB), g1 = __shfl(W[1], srcB), g2 = __shfl(W[2], srcB), g3 = __shfl(W[3], srcB); \
      union { uint u[4]; s16x8 v; } pf;                                       \
      pf.u[0] = hi ? e2 : e0; pf.u[1] = hi ? e3 : e1;                         \
      pf.u[2] = hi ? g2 : g0; pf.u[3] = hi ? g3 : g1;                         \
      _Pragma("unroll")                                                       \
      for (int nc = 0; nc < 4; ++nc)                                          \
        acc_o[nc] = MFMA16(pf.v, vb0[nc], acc_o[nc]);                         \
    }                                                                         \
    {                                                                         \
      uint e0 = __shfl(W[4], srcA), e1 = __shfl(W[5], srcA), e2 = __shfl(W[6], srcA), e3 = __shfl(W[7], srcA); \
      uint g0 = __shfl(W[4], srcB), g1 = __shfl(W[5], srcB), g2 = __shfl(W[6], srcB), g3 = __shfl(W[7], srcB); \
      union { uint u[4]; s16x8 v; } pf;                                       \
      pf.u[0] = hi ? e2 : e0; pf.u[1] = hi ? e3 : e1;                         \
      pf.u[2] = hi ? g2 : g0; pf.u[3] = hi ? g3 : g1;                         \
      _Pragma("unroll")                                                       \
      for (int nc = 0; nc < 4; ++nc)                                          \
        acc_o[nc] = MFMA16(pf.v, vb1[nc], acc_o[nc]);                         \
    }                                                                         \
  } while (0)

__global__ __launch_bounds__(256) void attn_k(
    const u16* __restrict__ Qw, const u16* __restrict__ Kw,
    const u16* __restrict__ Vtg,
    const u16* __restrict__ Bh_g, const u16* __restrict__ Bw_g,
    int S, float* __restrict__ Opart, float* __restrict__ Lpart,
    u16* __restrict__ Aout)
{
  __shared__ __align__(16) float BhL[48][64];   // [kh][local qrow]
  __shared__ __align__(16) float BwL[64][52];   // [local qrow][kw]

  // XCD swizzle: nwg = 864*S (div by 8). XCD x runs heads 3x..3x+2 only ->
  // per-XCD K/V working set 1.76 MB -> L2-resident.
  const int bid = blockIdx.x;
  const int xcd = bid & 7;
  const int local = bid >> 3;            // [0, 108*S)
  const int per_head = 36 * S;
  const int head_l = local / per_head;   // 0..2
  const int rem = local - head_l * per_head;
  const int qb = rem / S;
  const int z = rem - qb * S;
  const int bhd = xcd * 3 + head_l;
  const int q0 = qb << 6;
  const int span = NQ / S;               // 2304/1152/768 (mult of 48 & 128)
  const int kt_lo = z * span, kt_hi = kt_lo + span;

  const int t = threadIdx.x;
  const int w = t >> 6, l15 = t & 15, quad = (t >> 4) & 3;
  const float scale = 0.125f;   // 64^-0.5

  const u16* kbase  = Kw  + (size_t)bhd * NQ * HD;
  const u16* vtbase = Vtg + (size_t)bhd * HD * NQ;
  const int q0w = q0 + (w << 4);
  const int qrl = (w << 4) + l15;        // this lane's local q row

  // preload K tile 0 + Q frags (overlaps the LDS fill below)
  s16x8 kbA[8], kbB[8];
#pragma unroll
  for (int nc = 0; nc < 4; ++nc) {
    const u16* kp = kbase + (size_t)(kt_lo + (nc << 4) + l15) * HD + (quad << 3);
    kbA[2*nc]   = *(const s16x8*)(kp);
    kbA[2*nc+1] = *(const s16x8*)(kp + 32);
  }
  const u16* qfrag = Qw + ((size_t)bhd * NQ + q0w + l15) * HD + (quad << 3);
  s16x8 qa0 = *(const s16x8*)(qfrag);
  s16x8 qa1 = *(const s16x8*)(qfrag + 32);

  // ---- LDS fill from precomputed tables (coalesced fp16 reads)
  for (int e = t; e < 48 * 64; e += 256) {
    int c = e >> 6, r = e & 63;
    size_t gi = ((size_t)bhd * 48 + c) * NQ + q0 + r;
    BhL[c][r] = h2f(Bh_g[gi]);
    BwL[r][c] = h2f(Bw_g[gi]);
  }
  __syncthreads();   // bias tables visible

  f32x4 zero4 = {0.f, 0.f, 0.f, 0.f};
  f32x4 acc_o[4];
#pragma unroll
  for (int nc = 0; nc < 4; ++nc) acc_o[nc] = zero4;
  float l_st = 0.f;
  const int srcA = ((quad & 1) << 5) + l15;
  const int srcB = srcA + 16;
  const int hi = quad >> 1;
  int km = 0;                            // kt0 % 48 (kt_lo % 48 == 0)

  for (int kt0 = kt_lo; kt0 < kt_hi; kt0 += 128) {
    ATTN_TILE(kbA, kbB, 1, kt0, kt0 + 64, km);
    km += 16; if (km >= 48) km -= 48;
    int pref2 = (kt0 + 128) < kt_hi;
    ATTN_TILE(kbB, kbA, pref2, kt0 + 64, kt0 + 128, km);
    km += 16; if (km >= 48) km -= 48;
  }

  // reduce l across quads (each lane then has full sum for qrow = q0w+l15)
  l_st += __shfl_xor(l_st, 16);
  l_st += __shfl_xor(l_st, 32);

  if (S > 1) {
    // partial path: unnormalized f32 O + l per split
    float* Op = Opart + ((size_t)(z * HEADS + bhd) * NQ + q0) * HD;
#pragma unroll
    for (int r = 0; r < 4; ++r) {
      int row = (w << 4) + (quad << 2) + r;
#pragma unroll
      for (int nc = 0; nc < 4; ++nc)
        Op[(size_t)row * HD + (nc << 4) + l15] = acc_o[nc][r];
    }
    if (quad == 0)
      Lpart[(size_t)(z * HEADS + bhd) * NQ + q0w + l15] = l_st;
  } else {
    // direct path: divide by l (broadcast from lane l15 == 4*quad+r)
    int b_ = bhd / NHEAD, head = bhd - b_ * NHEAD;
    float invl = 1.f / l_st;
    int bsrc = (quad << 4) + (quad << 2);
#pragma unroll
    for (int r = 0; r < 4; ++r) {
      float inv = __shfl(invl, bsrc + r);
      int token = q0 + (w << 4) + (quad << 2) + r;
      u16* dst = Aout + ((size_t)b_ * NQ + token) * DIMC + (head << 6);
#pragma unroll
      for (int nc = 0; nc < 4; ++nc)
        dst[(nc << 4) + l15] = f2bf(acc_o[nc][r] * inv);
    }
  }
}

// ---------------------------------------------------------------------------
// K2b: combine split-K partials: O = (sum_z O_z) / (sum_z l_z), store bf16.
// ---------------------------------------------------------------------------
__global__ __launch_bounds__(256) void combine_k(
    const float* __restrict__ Op, const float* __restrict__ Lp,
    int S, u16* __restrict__ Aout)
{
  int idx = blockIdx.x * 256 + threadIdx.x;   // 0 .. 884735
  int m = idx / 192;                          // row 0..4607 (DIMC/4 = 192)
  int cq = idx - m * 192;
  int ccol = cq << 2;
  int head = ccol >> 6, d0 = ccol & 63;
  int b_ = (m >= NQ) ? 1 : 0;
  int n = m - b_ * NQ;
  int bh = b_ * NHEAD + head;
  float ox = 0.f, oy = 0.f, oz = 0.f, ow = 0.f, ls = 0.f;
  for (int zz = 0; zz < S; ++zz) {
    const float* ob = Op + ((size_t)(zz * HEADS + bh) * NQ + n) * HD + d0;
    float4 v = *(const float4*)ob;
    ox += v.x; oy += v.y; oz += v.z; ow += v.w;
    ls += Lp[(size_t)(zz * HEADS + bh) * NQ + n];
  }
  float inv = 1.f / ls;
  u16* dst = Aout + (size_t)m * DIMC + ccol;
  dst[0] = f2bf(ox * inv); dst[1] = f2bf(oy * inv);
  dst[2] = f2bf(oz * inv); dst[3] = f2bf(ow * inv);
}

// ---------------------------------------------------------------------------
// K3: output projection, MFMA (unchanged).
// ---------------------------------------------------------------------------
__global__ __launch_bounds__(256) void proj_gemm_k(
    const u16* __restrict__ A, const void* __restrict__ Wp,
    const void* __restrict__ Bp, const int* __restrict__ mode,
    void* __restrict__ Out)
{
  __shared__ __align__(16) u16 As[128][40];
  __shared__ __align__(16) u16 Bs[128][40];
  const int bf = mode[0];
  const int t = threadIdx.x;
  const int w = t >> 6, l15 = t & 15, quad = (t >> 4) & 3;
  const int wr = w >> 1, wc = w & 1;
  const int row0 = blockIdx.y << 7, col0 = blockIdx.x << 7;
  const int lr = t >> 1, lk = (t & 1) << 4;

  f32x4 zero4 = {0.f, 0.f, 0.f, 0.f};
  f32x4 acc[4][4];
#pragma unroll
  for (int i = 0; i < 4; ++i)
#pragma unroll
    for (int j = 0; j < 4; ++j) acc[i][j] = zero4;

  for (int kt = 0; kt < DIMC; kt += 32) {
    __syncthreads();
    *(uint4*)&As[lr][lk]     = *(const uint4*)(A + (size_t)(row0 + lr) * DIMC + kt + lk);
    *(uint4*)&As[lr][lk + 8] = *(const uint4*)(A + (size_t)(row0 + lr) * DIMC + kt + lk + 8);
    *(uint4*)&Bs[lr][lk]     = ld8_to_bf(Wp, (size_t)(col0 + lr) * DIMC + kt + lk, bf);
    *(uint4*)&Bs[lr][lk + 8] = ld8_to_bf(Wp, (size_t)(col0 + lr) * DIMC + kt + lk + 8, bf);
    __syncthreads();
    s16x8 af[4], bfr[4];
#pragma unroll
    for (int i = 0; i < 4; ++i)
      af[i] = *(const s16x8*)&As[(wr << 6) + (i << 4) + l15][quad << 3];
#pragma unroll
    for (int j = 0; j < 4; ++j)
      bfr[j] = *(const s16x8*)&Bs[(wc << 6) + (j << 4) + l15][quad << 3];
#pragma unroll
    for (int i = 0; i < 4; ++i)
#pragma unroll
      for (int j = 0; j < 4; ++j)
        acc[i][j] = MFMA16(af[i], bfr[j], acc[i][j]);
  }

#pragma unroll
  for (int jt = 0; jt < 4; ++jt) {
    int col = col0 + (wc << 6) + (jt << 4) + l15;
    float bv = ld1(Bp, col, bf);
#pragma unroll
    for (int i = 0; i < 4; ++i)
#pragma unroll
      for (int r = 0; r < 4; ++r) {
        int mrow = row0 + (wr << 6) + (i << 4) + (quad << 2) + r;
        float val = acc[i][jt][r] + bv;
        size_t off = (size_t)mrow * DIMC + col;
        if (bf) ((u16*)Out)[off] = f2bf(val);
        else    ((float*)Out)[off] = val;
      }
  }
}

// ---------------------------------------------------------------------------
extern "C" void kernel_launch(void* const* d_in, const int* in_sizes, int n_in,
                              void* d_out, int out_size, void* d_ws, size_t ws_size,
                              hipStream_t stream)
{
  const void* x    = d_in[0];   // (2,48,48,768)
  const void* rph  = d_in[1];   // (95,64)
  const void* rpw  = d_in[2];   // (95,64)
  const void* qkvw = d_in[3];   // (2304,768)
  const void* qkvb = d_in[4];   // (2304,)
  const void* pw   = d_in[5];   // (768,768)
  const void* pb   = d_in[6];   // (768,)

  // Workspace layout:
  //  [mode 16B] q,k bf16 (24,2304,64); vt bf16 (24,64,2304); aout bf16
  //  (2,2304,768)  -> base = 28,311,568 B
  //  bias tables fp16 (24,48,2304) x2   -> +10,616,832 B
  //  split-K partials f32 (S x O + S x l) if room.
  int* mode = (int*)d_ws;
  const size_t qkv_elems = (size_t)HEADS * NQ * HD;   // 3,538,944
  u16* q    = (u16*)((char*)d_ws + 16);
  u16* k    = q + qkv_elems;
  u16* vt   = k + qkv_elems;
  u16* aout = vt + qkv_elems;
  const size_t base = 16 + 4 * qkv_elems * 2;         // 28,311,568 B
  const size_t biasElems = (size_t)HEADS * 48 * NQ;   // 2,654,208 per table
  u16* bh_g = (u16*)((char*)d_ws + base);
  u16* bw_g = bh_g + biasElems;
  const size_t base2 = base + 2 * biasElems * 2;      // +10,616,832 B
  const size_t perO = (size_t)HEADS * NQ * HD * 4;    // 14,155,776 B
  const size_t perL = (size_t)HEADS * NQ * 4;         //    221,184 B

  int S = 1;
  if (ws_size >= base2 + 3 * (perO + perL)) S = 3;
  else if (ws_size >= base2 + 2 * (perO + perL)) S = 2;
  float* opart = (float*)((char*)d_ws + base2);
  float* lpart = (float*)((char*)d_ws + base2 + (size_t)S * perO);

  detect_k<<<1, 64, 0, stream>>>((const u16*)x, mode);
  qkv_gemm_k<<<dim3(18, 36), 256, 0, stream>>>(x, qkvw, qkvb, mode, q, k, vt);
  bias_gemm_k<<<dim3(432), 256, 0, stream>>>(q, rph, rpw, mode, bh_g, bw_g);
  attn_k<<<dim3(864 * S), 256, 0, stream>>>(q, k, vt, bh_g, bw_g,
                                            S, opart, lpart, aout);
  if (S > 1)
    combine_k<<<dim3(3456), 256, 0, stream>>>(opart, lpart, S, aout);
  proj_gemm_k<<<dim3(6, 36), 256, 0, stream>>>(aout, pw, pb, mode, d_out);
}